// Round 1
// baseline (1955.203 us; speedup 1.0000x reference)
//
#include <hip/hip_runtime.h>
#include <math.h>

// Problem constants (match reference)
#define T_STEPS 8
#define N_NODES 20000
#define F_IN    128
#define H_DIM   256
#define E_EDGES 320000

// ---------------- CSR build ----------------

__global__ void count_kernel(const int* __restrict__ dst, int* __restrict__ counts, int E) {
    int e = blockIdx.x * blockDim.x + threadIdx.x;
    if (e < E) atomicAdd(&counts[dst[e]], 1);
}

// single-block exclusive scan over counts[n] -> row_ptr[n+1], cursors[n]
__global__ void scan_kernel(const int* __restrict__ counts, int* __restrict__ row_ptr,
                            int* __restrict__ cursors, int n) {
    __shared__ int buf[1024];
    __shared__ int carry_s;
    int tid = threadIdx.x;
    if (tid == 0) carry_s = 0;
    __syncthreads();
    for (int base = 0; base < n; base += 1024) {
        int i = base + tid;
        int v = (i < n) ? counts[i] : 0;
        buf[tid] = v;
        __syncthreads();
        // Hillis-Steele inclusive scan
        for (int off = 1; off < 1024; off <<= 1) {
            int t = (tid >= off) ? buf[tid - off] : 0;
            __syncthreads();
            buf[tid] += t;
            __syncthreads();
        }
        int incl = buf[tid];
        int carry = carry_s;
        if (i < n) {
            int ex = carry + incl - v;
            row_ptr[i] = ex;
            cursors[i] = ex;
        }
        __syncthreads();
        if (tid == 1023) carry_s = carry + incl;
        __syncthreads();
    }
    if (tid == 0) row_ptr[n] = carry_s;
}

__global__ void fill_kernel(const int* __restrict__ src, const int* __restrict__ dst,
                            int* __restrict__ cursors, int* __restrict__ col, int E) {
    int e = blockIdx.x * blockDim.x + threadIdx.x;
    if (e < E) {
        int d = dst[e];
        int p = atomicAdd(&cursors[d], 1);
        col[p] = src[e];
    }
}

// ---------------- gather: agg[i,:] = sum_{j in row i} s[col[j],:] ----------------
// one wave (64 lanes) per node, float4 per lane (64*4 = 256 = H)

__global__ __launch_bounds__(256) void gather_kernel(
        const float* __restrict__ s, const int* __restrict__ row_ptr,
        const int* __restrict__ col, float* __restrict__ agg, int n) {
    int wave = threadIdx.x >> 6;
    int lane = threadIdx.x & 63;
    int node = blockIdx.x * 4 + wave;
    if (node >= n) return;
    int beg = row_ptr[node], end = row_ptr[node + 1];
    const float4* s4 = (const float4*)s;
    float ax = 0.f, ay = 0.f, az = 0.f, aw = 0.f;
    float bx = 0.f, by = 0.f, bz = 0.f, bw = 0.f;
    int j = beg;
    for (; j + 1 < end; j += 2) {
        int c0 = col[j], c1 = col[j + 1];
        float4 v0 = s4[(size_t)c0 * 64 + lane];
        float4 v1 = s4[(size_t)c1 * 64 + lane];
        ax += v0.x; ay += v0.y; az += v0.z; aw += v0.w;
        bx += v1.x; by += v1.y; bz += v1.z; bw += v1.w;
    }
    if (j < end) {
        int c = col[j];
        float4 v = s4[(size_t)c * 64 + lane];
        ax += v.x; ay += v.y; az += v.z; aw += v.w;
    }
    float4 o;
    o.x = ax + bx; o.y = ay + by; o.z = az + bz; o.w = aw + bw;
    ((float4*)agg)[(size_t)node * 64 + lane] = o;
}

// ---------------- fused update GEMM ----------------
// s_out[m,n] = leak*tanh( sum_k X[m,k]*Win[n,k] + sum_k AGG[m,k]*Wrec[n,k] )
//              + (1-leak)*s_old[m,n]
// X: M x K1 row-major; AGG: M x 256 (may be null); Win: 256 x K1; Wrec: 256 x 256
// BM=64, BN=64, BK=32; 256 threads; 4x4 microtile

#define BM 64
#define BN 64
#define BK 32
#define APAD 4

__global__ __launch_bounds__(256) void update_kernel(
        const float* __restrict__ X, int K1,
        const float* __restrict__ AGG,
        const float* __restrict__ Win,
        const float* __restrict__ Wrec,
        const float* __restrict__ s_old,
        float* __restrict__ s_out,
        int M, const float* __restrict__ leak_ptr) {
    __shared__ float As[BK][BM + APAD];
    __shared__ float Bs[BK][BN + APAD];

    int tid = threadIdx.x;
    int tx = tid & 15;          // 0..15 -> 4 output cols each
    int ty = tid >> 4;          // 0..15 -> 4 output rows each
    int m0 = blockIdx.x * BM;
    int n0 = blockIdx.y * BN;

    float acc[4][4] = {};

    int kt1 = K1 / BK;
    int kt2 = (AGG != nullptr) ? (H_DIM / BK) : 0;
    int ktn = kt1 + kt2;

    for (int kt = 0; kt < ktn; ++kt) {
        const float* Aptr;
        const float* Bptr;
        int lda, kk;
        if (kt < kt1) { Aptr = X;   Bptr = Win;  lda = K1;    kk = kt * BK; }
        else          { Aptr = AGG; Bptr = Wrec; lda = H_DIM; kk = (kt - kt1) * BK; }

        // load A tile (64 x 32) as 512 float4, 2 per thread
        #pragma unroll
        for (int r = 0; r < 2; ++r) {
            int idx = tid + r * 256;
            int row = idx >> 3;       // 0..63
            int cv  = idx & 7;        // float4 within the 32-wide K slab
            int grow = m0 + row;
            float4 v = make_float4(0.f, 0.f, 0.f, 0.f);
            if (grow < M) v = *(const float4*)(Aptr + (size_t)grow * lda + kk + cv * 4);
            As[cv * 4 + 0][row] = v.x;
            As[cv * 4 + 1][row] = v.y;
            As[cv * 4 + 2][row] = v.z;
            As[cv * 4 + 3][row] = v.w;
        }
        // load B tile (64 x 32) from W rows n0..n0+63 (N_out=256 exact, no guard)
        #pragma unroll
        for (int r = 0; r < 2; ++r) {
            int idx = tid + r * 256;
            int row = idx >> 3;
            int cv  = idx & 7;
            float4 v = *(const float4*)(Bptr + (size_t)(n0 + row) * lda + kk + cv * 4);
            Bs[cv * 4 + 0][row] = v.x;
            Bs[cv * 4 + 1][row] = v.y;
            Bs[cv * 4 + 2][row] = v.z;
            Bs[cv * 4 + 3][row] = v.w;
        }
        __syncthreads();

        #pragma unroll
        for (int k = 0; k < BK; ++k) {
            float4 a = *(const float4*)&As[k][ty * 4];
            float4 b = *(const float4*)&Bs[k][tx * 4];
            float av[4] = {a.x, a.y, a.z, a.w};
            float bv[4] = {b.x, b.y, b.z, b.w};
            #pragma unroll
            for (int i = 0; i < 4; ++i)
                #pragma unroll
                for (int jj = 0; jj < 4; ++jj)
                    acc[i][jj] += av[i] * bv[jj];
        }
        __syncthreads();
    }

    float leak = leak_ptr[0];
    float il = 1.0f - leak;
    #pragma unroll
    for (int i = 0; i < 4; ++i) {
        int m = m0 + ty * 4 + i;
        if (m >= M) continue;
        int n = n0 + tx * 4;
        float4 old = *(const float4*)(s_old + (size_t)m * H_DIM + n);
        float4 o;
        o.x = leak * tanhf(acc[i][0]) + il * old.x;
        o.y = leak * tanhf(acc[i][1]) + il * old.y;
        o.z = leak * tanhf(acc[i][2]) + il * old.z;
        o.w = leak * tanhf(acc[i][3]) + il * old.w;
        *(float4*)(s_out + (size_t)m * H_DIM + n) = o;
    }
}

// ---------------- launch ----------------

extern "C" void kernel_launch(void* const* d_in, const int* in_sizes, int n_in,
                              void* d_out, int out_size, void* d_ws, size_t ws_size,
                              hipStream_t stream) {
    const float* x        = (const float*)d_in[0];   // (T, N, F)
    const int*   edge     = (const int*)d_in[1];     // (2, E)
    const float* w_in0    = (const float*)d_in[2];   // (H, F)
    const float* w_rec0   = (const float*)d_in[3];   // (H, H)
    const float* w_in1    = (const float*)d_in[4];   // (H, H)
    const float* w_rec1   = (const float*)d_in[5];   // (H, H)
    const float* leak_ptr = (const float*)d_in[6];   // scalar

    const int* src = edge;            // edge_index[0]
    const int* dst = edge + E_EDGES;  // edge_index[1]

    float* s1 = (float*)d_out;        // layer-1 state lives in d_out (in-place)

    // workspace layout
    char* ws = (char*)d_ws;
    float* s0  = (float*)ws;                                  // N*H floats
    float* agg = s0 + (size_t)N_NODES * H_DIM;                // N*H floats
    int* row_ptr = (int*)(agg + (size_t)N_NODES * H_DIM);     // N+1
    int* cursors = row_ptr + (N_NODES + 1);                   // N
    int* counts  = cursors + N_NODES;                         // N
    int* col     = counts + N_NODES;                          // E

    // zero-init states and counts
    hipMemsetAsync(s0, 0, (size_t)N_NODES * H_DIM * sizeof(float), stream);
    hipMemsetAsync(s1, 0, (size_t)N_NODES * H_DIM * sizeof(float), stream);
    hipMemsetAsync(counts, 0, (size_t)N_NODES * sizeof(int), stream);

    // CSR build (by dst)
    count_kernel<<<(E_EDGES + 255) / 256, 256, 0, stream>>>(dst, counts, E_EDGES);
    scan_kernel<<<1, 1024, 0, stream>>>(counts, row_ptr, cursors, N_NODES);
    fill_kernel<<<(E_EDGES + 255) / 256, 256, 0, stream>>>(src, dst, cursors, col, E_EDGES);

    dim3 ggrid((N_NODES + 3) / 4);
    dim3 ugrid((N_NODES + BM - 1) / BM, H_DIM / BN);

    for (int t = 0; t < T_STEPS; ++t) {
        const float* xt = x + (size_t)t * N_NODES * F_IN;
        if (t == 0) {
            // states are zero: agg contributions are zero, skip gathers
            update_kernel<<<ugrid, 256, 0, stream>>>(xt, F_IN, nullptr, w_in0, w_rec0,
                                                     s0, s0, N_NODES, leak_ptr);
            update_kernel<<<ugrid, 256, 0, stream>>>(s0, H_DIM, nullptr, w_in1, w_rec1,
                                                     s1, s1, N_NODES, leak_ptr);
        } else {
            gather_kernel<<<ggrid, 256, 0, stream>>>(s0, row_ptr, col, agg, N_NODES);
            update_kernel<<<ugrid, 256, 0, stream>>>(xt, F_IN, agg, w_in0, w_rec0,
                                                     s0, s0, N_NODES, leak_ptr);
            gather_kernel<<<ggrid, 256, 0, stream>>>(s1, row_ptr, col, agg, N_NODES);
            update_kernel<<<ugrid, 256, 0, stream>>>(s0, H_DIM, agg, w_in1, w_rec1,
                                                     s1, s1, N_NODES, leak_ptr);
        }
    }
}